// Round 5
// baseline (130.889 us; speedup 1.0000x reference)
//
#include <hip/hip_runtime.h>
#include <hip/hip_bf16.h>

// B=64, M=16, T=2048, L=64, K=32, N=1985
#define B_ 64
#define M_ 16
#define T_ 2048
#define L_ 64
#define K_ 32
#define N_ (T_ - L_ + 1)   // 1985
#define TN 64              // n-positions per block
#define NT_ 32             // n-tiles (grid x)
#define NTH 256            // 4 waves: wave w owns n-subtile [16w,16w+16), both k-tiles
#define XROW 144           // per-plane row elems; need j<=123. 144 elems = 72 dw
                           // == 8 (mod 32) -> planes at bank offsets {0,8,16,24}:
                           // uniform 4 touches/bank = the 512B/wave floor.
// Blocked pen layout: pen[k][nt][m][64], padded to n=2048 (pad rows get pen=2,
// masked at the final min). Full 128B-line utilization, no guards in m-loop.
#define PENK (NT_ * M_ * 64)        // 32768 floats per k
#define PENSZ (K_ * PENK)           // 1,048,576 floats = 4 MB

typedef __attribute__((ext_vector_type(8))) short bf16x8;
typedef __attribute__((ext_vector_type(4))) float f32x4;

__device__ __forceinline__ unsigned short f2bf(float f) {
    __hip_bfloat16 h = __float2bfloat16(f);
    return __builtin_bit_cast(unsigned short, h);
}

__device__ __forceinline__ float elu_pen(float p) {
    return (p < 0.f) ? (2.f - p) : (__expf(-p) + 1.f);   // elu(-p) + 2
}

// Fused init: out = +inf bits, pen in blocked layout. (ss now in-kernel via shfl.)
__global__ void pen_init_kernel(const float* __restrict__ pmap,
                                float* __restrict__ pen,
                                unsigned* __restrict__ out) {
    const int gid = blockIdx.x * 256 + threadIdx.x;
    if (gid < B_ * K_) out[gid] = 0x7F800000u;  // +inf
    if (gid < PENSZ / 4) {
        const int o = gid * 4;
        const int nin = o & 63;
        const int m   = (o >> 6) & 15;
        const int nt  = (o >> 10) & 31;
        const int k   = o >> 15;
        const int n   = nt * TN + nin;
        const float* src = pmap + ((size_t)k * M_ + m) * N_ + n;
        float p[4];
        if (n + 3 < N_) {
            float4 v = *(const float4*)src;
            p[0] = v.x; p[1] = v.y; p[2] = v.z; p[3] = v.w;
        } else {
#pragma unroll
            for (int i = 0; i < 4; ++i) p[i] = (n + i < N_) ? src[i] : 0.f;
        }
        float4 r;
        r.x = elu_pen(p[0]); r.y = elu_pen(p[1]);
        r.z = elu_pen(p[2]); r.w = elu_pen(p[3]);
        *(float4*)(pen + o) = r;
    }
}

// LDS: 18432 (xbuf4) + 4096 (sqw) = 22528 B — st buffer deleted (b-frags come
// straight from global shp). Theory: LDS is the residency limiter (m132-style
// cap well below the 160K pool); 27136->22528 should buy +1 resident block/CU.
// __launch_bounds__(256, 6): VGPR cap 85 (r0-family body measured 40-56).
__global__ __launch_bounds__(NTH, 6)
void shapelet_mfma_kernel(const float* __restrict__ x,
                          const float* __restrict__ shp,
                          const float* __restrict__ pen,
                          unsigned* __restrict__ out) {
    __shared__ __align__(16) unsigned short xbuf4[M_][4][XROW]; // 4 shifted bf16 planes
    __shared__ __align__(16) float sqw[M_][TN];                 // fp32 sliding sum x^2

    const int tid = threadIdx.x;
    const int bx = blockIdx.x;
    const int n0 = bx * TN;
    const int b  = blockIdx.y;
    const bool fast = (n0 + 2 * TN <= T_);   // false only for last tile (n0=1984)

    // ---- stage x as 4 shifted bf16 planes (ALL 256 threads, r0 arrangement) ----
    const float* xb = x + ((size_t)b * M_) * T_ + n0;
    for (int g = tid; g < M_ * 31; g += NTH) {
        const int m = g / 31, j4 = (g - m * 31) * 4;     // j4 in {0,4,...,120}
        const float* src = xb + m * T_ + j4;
        float h[8];
        if (fast) {
            float4 v0 = *(const float4*)src;
            float4 v1 = *(const float4*)(src + 4);
            h[0] = v0.x; h[1] = v0.y; h[2] = v0.z; h[3] = v0.w;
            h[4] = v1.x; h[5] = v1.y; h[6] = v1.z; h[7] = v1.w;
        } else {
#pragma unroll
            for (int i = 0; i < 8; ++i)
                h[i] = (n0 + j4 + i < T_) ? src[i] : 0.f;
        }
        unsigned short hb[8];
#pragma unroll
        for (int i = 0; i < 8; ++i) hb[i] = f2bf(h[i]);
#pragma unroll
        for (int s = 0; s < 4; ++s) {
            ushort4 sv = { hb[s], hb[s + 1], hb[s + 2], hb[s + 3] };
            *(ushort4*)&xbuf4[m][s][j4] = sv;
        }
    }
    // ---- sqw sliding window: 8 threads per m, 8 n each; 4-way ILP base sum ----
    if (tid < M_ * 8) {
        const int m = tid >> 3, j0 = (tid & 7) * 8;
        const float* xr = x + ((size_t)b * M_ + m) * T_ + n0;
        if (fast) {
            float s0 = 0.f, s1 = 0.f, s2 = 0.f, s3 = 0.f;
#pragma unroll
            for (int qd = 0; qd < 16; ++qd) {
                float4 v = *(const float4*)(xr + j0 + qd * 4);
                s0 = fmaf(v.x, v.x, s0); s1 = fmaf(v.y, v.y, s1);
                s2 = fmaf(v.z, v.z, s2); s3 = fmaf(v.w, v.w, s3);
            }
            float s = (s0 + s1) + (s2 + s3);
            sqw[m][j0] = s;
#pragma unroll
            for (int d = 1; d < 8; ++d) {
                float a = xr[j0 + d + L_ - 1], r = xr[j0 + d - 1];
                s += a * a - r * r;
                sqw[m][j0 + d] = s;
            }
        } else {
            float s = 0.f;
            for (int l = 0; l < L_; ++l) {
                float v = (n0 + j0 + l < T_) ? xr[j0 + l] : 0.f;
                s = fmaf(v, v, s);
            }
            sqw[m][j0] = s;
            for (int d = 1; d < 8; ++d) {
                float a = (n0 + j0 + d + L_ - 1 < T_) ? xr[j0 + d + L_ - 1] : 0.f;
                float r = (n0 + j0 + d - 1 < T_) ? xr[j0 + d - 1] : 0.f;
                s += a * a - r * r;
                sqw[m][j0 + d] = s;
            }
        }
    }

    // ---- per-lane MFMA coordinates ----
    const int lane = tid & 63;
    const int w  = tid >> 6;       // wave -> n-subtile [16w, 16w+16)
    const int rl = lane & 15;      // A-row (n within subtile) / B-col (k within tile)
    const int q  = lane >> 4;      // quad
    const int sp = rl & 3;                          // shift plane
    const int e0 = 16 * w + 8 * q + (rl & ~3);      // 4-aligned elem base (max 84)
    const int eq = e0 >> 2;                         // uint2 index (max 21; +9 fits)
    const int nrow = n0 + 16 * w + 4 * q;           // lane's 4 output rows: nrow + reg

    // ---- b-frags + ss directly from global shp (st LDS buffer deleted) ----
    // lane holds shp[16t+rl][8q+32h .. +7]; the 4 q-lanes of a given rl jointly
    // cover all 64 l -> ss via 2 shfl_xor adds. Loads are L3/L1-warm (8 KB total).
    bf16x8 bfr[2][2];
    float ssk0 = 0.f, ssk1 = 0.f;
#pragma unroll
    for (int t = 0; t < 2; ++t) {
        float* ssp = t ? &ssk1 : &ssk0;
#pragma unroll
        for (int h = 0; h < 2; ++h) {
            const float* sp_ = shp + (16 * t + rl) * L_ + 8 * q + 32 * h;
            float4 a = *(const float4*)sp_;
            float4 c = *(const float4*)(sp_ + 4);
            *ssp = fmaf(a.x, a.x, *ssp); *ssp = fmaf(a.y, a.y, *ssp);
            *ssp = fmaf(a.z, a.z, *ssp); *ssp = fmaf(a.w, a.w, *ssp);
            *ssp = fmaf(c.x, c.x, *ssp); *ssp = fmaf(c.y, c.y, *ssp);
            *ssp = fmaf(c.z, c.z, *ssp); *ssp = fmaf(c.w, c.w, *ssp);
            bf16x8 f = { (short)f2bf(a.x), (short)f2bf(a.y), (short)f2bf(a.z),
                         (short)f2bf(a.w), (short)f2bf(c.x), (short)f2bf(c.y),
                         (short)f2bf(c.z), (short)f2bf(c.w) };
            bfr[t][h] = f;
        }
    }
    ssk0 += __shfl_xor(ssk0, 16); ssk0 += __shfl_xor(ssk0, 32);
    ssk1 += __shfl_xor(ssk1, 16); ssk1 += __shfl_xor(ssk1, 32);

    __syncthreads();

    // Blocked pen: rows of 64 floats per m; lane reads nin = 16w+4q .. +3.
    const float* pb0 = pen + (size_t)rl * PENK + (size_t)bx * (M_ * 64) + (16 * w + 4 * q);
    const float* pb1 = pb0 + (size_t)16 * PENK;   // k = rl + 16

    f32x4 wd0 = (f32x4)0.f, wd1 = (f32x4)0.f;
    const f32x4 zero = (f32x4)0.f;

    // r0-measured-best loop shape: unroll 2, loads in body, compiler-scheduled.
    // Pen loads unguarded (blocked layout padded); OOB rows masked at the min.
#pragma unroll 2
    for (int m = 0; m < M_; ++m) {
        float4 pm0 = *(const float4*)(pb0 + (size_t)m * 64);
        float4 pm1 = *(const float4*)(pb1 + (size_t)m * 64);

        const uint2* prow = (const uint2*)&xbuf4[m][sp][0];
        uint2 lo0 = prow[eq],     hi0 = prow[eq + 1];
        uint2 lo1 = prow[eq + 8], hi1 = prow[eq + 9];
        union { uint2 u2[2]; bf16x8 v; } fa0, fa1;
        fa0.u2[0] = lo0; fa0.u2[1] = hi0;
        fa1.u2[0] = lo1; fa1.u2[1] = hi1;

        f32x4 c0_ = __builtin_amdgcn_mfma_f32_16x16x32_bf16(fa0.v, bfr[0][0], zero, 0, 0, 0);
        c0_       = __builtin_amdgcn_mfma_f32_16x16x32_bf16(fa1.v, bfr[0][1], c0_, 0, 0, 0);
        f32x4 c1_ = __builtin_amdgcn_mfma_f32_16x16x32_bf16(fa0.v, bfr[1][0], zero, 0, 0, 0);
        c1_       = __builtin_amdgcn_mfma_f32_16x16x32_bf16(fa1.v, bfr[1][1], c1_, 0, 0, 0);

        const float pe0[4] = { pm0.x, pm0.y, pm0.z, pm0.w };
        const float pe1[4] = { pm1.x, pm1.y, pm1.z, pm1.w };
        f32x4 sq = *(const f32x4*)&sqw[m][16 * w + 4 * q];
#pragma unroll
        for (int r = 0; r < 4; ++r) {
            float u0 = fmaf(-2.f, c0_[r], sq[r] + ssk0);
            wd0[r] = fmaf(pe0[r], u0, wd0[r]);
            float u1 = fmaf(-2.f, c1_[r], sq[r] + ssk1);
            wd1[r] = fmaf(pe1[r], u1, wd1[r]);
        }
    }

    // ---- min: 4 rows -> quads (shfl) -> LDS cross-wave -> 1 atomic per (b,k) ----
    __syncthreads();                       // sqw reads done; reuse as scratch
    float* red = (float*)&sqw[0][0];       // [4 waves][32]
#pragma unroll
    for (int t = 0; t < 2; ++t) {
        float lmin = __int_as_float(0x7F800000);
        const f32x4 wdv = t ? wd1 : wd0;
#pragma unroll
        for (int r = 0; r < 4; ++r)
            if (nrow + r < N_) lmin = fminf(lmin, wdv[r]);
        lmin = fminf(lmin, __shfl_xor(lmin, 16));
        lmin = fminf(lmin, __shfl_xor(lmin, 32));
        if (q == 0) red[w * 32 + t * 16 + rl] = lmin;
    }
    __syncthreads();
    if (tid < K_) {
        float v = fminf(fminf(red[tid], red[32 + tid]),
                        fminf(red[64 + tid], red[96 + tid]));
        atomicMin(out + (size_t)b * K_ + tid, __float_as_uint(fmaxf(v, 0.f)));
    }
}

extern "C" void kernel_launch(void* const* d_in, const int* in_sizes, int n_in,
                              void* d_out, int out_size, void* d_ws, size_t ws_size,
                              hipStream_t stream) {
    const float* x    = (const float*)d_in[0];   // (B, M, T)
    const float* shp  = (const float*)d_in[1];   // (K, L)
    const float* pmap = (const float*)d_in[2];   // (K, M, N)
    unsigned* out = (unsigned*)d_out;            // (B, K) float bits
    float* pen   = (float*)d_ws;                 // blocked pen, 4 MB

    pen_init_kernel<<<dim3(PENSZ / 4 / 256), dim3(256), 0, stream>>>(pmap, pen, out);

    dim3 grid(NT_, B_);                          // 32 x 64 = 2048 blocks
    shapelet_mfma_kernel<<<grid, dim3(NTH), 0, stream>>>(x, shp, pen, out);
}

// Round 6
// 109.617 us; speedup vs baseline: 1.1941x; 1.1941x over previous
//
#include <hip/hip_runtime.h>
#include <hip/hip_bf16.h>

// B=64, M=16, T=2048, L=64, K=32, N=1985
#define B_ 64
#define M_ 16
#define T_ 2048
#define L_ 64
#define K_ 32
#define N_ (T_ - L_ + 1)   // 1985
#define KMN (K_ * M_ * N_) // 1,016,320 (= 4 * 254,080 exactly)
#define TN 64              // n-positions per block
#define NTH 256            // 4 waves: wave w owns n-subtile [16w,16w+16), both k-tiles
#define NBSEQ 4            // batches per block, processed SEQUENTIALLY (r0 inner
                           // structure per batch; only the work mapping changes:
                           // 2048 -> 512 workgroups, 4x longer-lived blocks)
#define XROW 144           // per-plane row elems; need j<=123. 144 elems = 72 dw
                           // == 8 (mod 32) -> planes at bank offsets {0,8,16,24}:
                           // uniform 4 touches/bank = the 512B/wave floor.
#define STSTR 72           // st row stride elems (16B-aligned b128 reads)
#define SQSTR 64           // sqw row stride

typedef __attribute__((ext_vector_type(8))) short bf16x8;
typedef __attribute__((ext_vector_type(4))) float f32x4;

__device__ __forceinline__ unsigned short f2bf(float f) {
    __hip_bfloat16 h = __float2bfloat16(f);
    return __builtin_bit_cast(unsigned short, h);
}

// pen[i] = elu(-pmap[i]) + 2 (flat over K*M*N, r0 layout); ss[k] = sum shp^2;
// out[] = +inf. 2 float4 items per thread -> half the init dispatches of r0.
__global__ void pen_init_kernel(const float* __restrict__ pmap,
                                const float* __restrict__ shp,
                                float* __restrict__ pen,
                                float* __restrict__ ss_ws,
                                unsigned* __restrict__ out) {
    const int gid = blockIdx.x * 256 + threadIdx.x;
    if (gid < B_ * K_) out[gid] = 0x7F800000u;  // +inf
    if (gid < K_) {
        float s = 0.f;
        for (int l = 0; l < L_; ++l) { float v = shp[gid * L_ + l]; s = fmaf(v, v, s); }
        ss_ws[gid] = s;
    }
#pragma unroll
    for (int half = 0; half < 2; ++half) {
        const int item = gid + half * (KMN / 8);     // KMN/4 = 254080 = 2*127040
        if (item < KMN / 4) {
            const int i4 = item * 4;
            float4 p = *(const float4*)(pmap + i4);
            float4 r;
            r.x = (p.x < 0.f) ? (2.f - p.x) : (__expf(-p.x) + 1.f);
            r.y = (p.y < 0.f) ? (2.f - p.y) : (__expf(-p.y) + 1.f);
            r.z = (p.z < 0.f) ? (2.f - p.z) : (__expf(-p.z) + 1.f);
            r.w = (p.w < 0.f) ? (2.f - p.w) : (__expf(-p.w) + 1.f);
            *(float4*)(pen + i4) = r;
        }
    }
}

// EXACT r0 inner structure (measured best: 42.9us, 40 VGPR, occ 33%), wrapped in
// a sequential 4-batch loop. LDS: 18432 + 4608 + 4096 = 27136 B (6 eligible/CU).
__global__ __launch_bounds__(NTH, 2)
void shapelet_mfma_kernel(const float* __restrict__ x,
                          const float* __restrict__ shp,
                          const float* __restrict__ pen,
                          const float* __restrict__ ss_ws,
                          unsigned* __restrict__ out) {
    __shared__ __align__(16) unsigned short xbuf4[M_][4][XROW];
    __shared__ __align__(16) unsigned short st[K_][STSTR];   // shapelets bf16
    __shared__ __align__(16) float sqw[M_][SQSTR];           // fp32 sliding sum x^2

    const int tid = threadIdx.x;
    const int bx = blockIdx.x;
    const int n0 = bx * TN;
    const bool fast = (n0 + 128 <= T_);   // false only for last tile (n0=1984)

    // ---- per-lane MFMA coordinates (r0) ----
    const int lane = tid & 63;
    const int w  = tid >> 6;       // wave -> n-subtile [16w, 16w+16)
    const int rl = lane & 15;      // A-row (n within subtile) / B-col (k within tile)
    const int q  = lane >> 4;      // quad
    const int sp = rl & 3;                          // shift plane
    const int e0 = 16 * w + 8 * q + (rl & ~3);      // 4-aligned elem base (max 84)
    const int eq = e0 >> 2;                         // uint2 index (max 21; +9 fits)
    const int nrow = n0 + 16 * w + 4 * q;           // lane's 4 output rows: nrow + reg

    // ---- stage shapelets st[k][l] bf16 — ONCE per block (reused for 4 batches) ----
    for (int i = tid; i < K_ * 16; i += NTH) {
        const int k = i >> 4, l4 = (i & 15) * 4;
        float4 v = *(const float4*)(shp + k * L_ + l4);
        ushort4 sv = { f2bf(v.x), f2bf(v.y), f2bf(v.z), f2bf(v.w) };
        *(ushort4*)&st[k][l4] = sv;
    }
    const float ssk0 = ss_ws[rl], ssk1 = ss_ws[16 + rl];
    __syncthreads();

    // b_frags (registers, whole kernel; st never overwritten): st[16t+rl][8q+32h..+7]
    bf16x8 bfr[2][2];
#pragma unroll
    for (int t = 0; t < 2; ++t)
#pragma unroll
        for (int h = 0; h < 2; ++h)
            bfr[t][h] = *(const bf16x8*)&st[16 * t + rl][8 * q + 32 * h];

    const float* pr0_base = pen + (size_t)rl * (M_ * N_) + nrow;   // k = rl
    const f32x4 zero = (f32x4)0.f;

    for (int bb = 0; bb < NBSEQ; ++bb) {
        const int b = blockIdx.y * NBSEQ + bb;

        // ---- stage x as 4 shifted bf16 planes (r0: all 256 threads) ----
        const float* xb = x + ((size_t)b * M_) * T_ + n0;
        for (int g = tid; g < M_ * 31; g += NTH) {
            const int m = g / 31, j4 = (g - m * 31) * 4;     // j4 in {0,4,...,120}
            const float* src = xb + m * T_ + j4;
            float h[8];
            if (fast) {
                float4 v0 = *(const float4*)src;
                float4 v1 = *(const float4*)(src + 4);
                h[0] = v0.x; h[1] = v0.y; h[2] = v0.z; h[3] = v0.w;
                h[4] = v1.x; h[5] = v1.y; h[6] = v1.z; h[7] = v1.w;
            } else {
#pragma unroll
                for (int i = 0; i < 8; ++i)
                    h[i] = (n0 + j4 + i < T_) ? src[i] : 0.f;
            }
            unsigned short hb[8];
#pragma unroll
            for (int i = 0; i < 8; ++i) hb[i] = f2bf(h[i]);
#pragma unroll
            for (int s = 0; s < 4; ++s) {
                ushort4 sv = { hb[s], hb[s + 1], hb[s + 2], hb[s + 3] };
                *(ushort4*)&xbuf4[m][s][j4] = sv;
            }
        }
        // ---- sqw fp32 sliding window (r0: 8 threads per m, 8 n each) ----
        if (tid < M_ * 8) {
            const int m = tid >> 3, j0 = (tid & 7) * 8;
            const float* xr = x + ((size_t)b * M_ + m) * T_ + n0;
            float s = 0.f;
            if (fast) {
#pragma unroll
                for (int qd = 0; qd < 16; ++qd) {
                    float4 v = *(const float4*)(xr + j0 + qd * 4);
                    s = fmaf(v.x, v.x, s); s = fmaf(v.y, v.y, s);
                    s = fmaf(v.z, v.z, s); s = fmaf(v.w, v.w, s);
                }
                sqw[m][j0] = s;
#pragma unroll
                for (int d = 1; d < 8; ++d) {
                    float a = xr[j0 + d + L_ - 1], r = xr[j0 + d - 1];
                    s += a * a - r * r;
                    sqw[m][j0 + d] = s;
                }
            } else {
                for (int l = 0; l < L_; ++l) {
                    float v = (n0 + j0 + l < T_) ? xr[j0 + l] : 0.f;
                    s = fmaf(v, v, s);
                }
                sqw[m][j0] = s;
                for (int d = 1; d < 8; ++d) {
                    float a = (n0 + j0 + d + L_ - 1 < T_) ? xr[j0 + d + L_ - 1] : 0.f;
                    float r = (n0 + j0 + d - 1 < T_) ? xr[j0 + d - 1] : 0.f;
                    s += a * a - r * r;
                    sqw[m][j0 + d] = s;
                }
            }
        }
        __syncthreads();

        const float* pr0 = pr0_base;                       // k = rl
        const float* pr1 = pr0 + (size_t)16 * M_ * N_;     // k = rl+16

        f32x4 wd0 = (f32x4)0.f, wd1 = (f32x4)0.f;

        // ---- r0 m-loop verbatim: unroll 2, loads in body ----
#pragma unroll 2
        for (int m = 0; m < M_; ++m) {
            float4 p0, p1;
            if (fast) {
                p0 = *(const float4*)(pr0 + (size_t)m * N_);
                p1 = *(const float4*)(pr1 + (size_t)m * N_);
            } else {
                p0 = make_float4(2.f, 2.f, 2.f, 2.f);   // masked at the min
                p1 = make_float4(2.f, 2.f, 2.f, 2.f);
                const float* r0_ = pr0 + (size_t)m * N_;
                const float* r1_ = pr1 + (size_t)m * N_;
                if (nrow     < N_) { p0.x = r0_[0]; p1.x = r1_[0]; }
                if (nrow + 1 < N_) { p0.y = r0_[1]; p1.y = r1_[1]; }
                if (nrow + 2 < N_) { p0.z = r0_[2]; p1.z = r1_[2]; }
                if (nrow + 3 < N_) { p0.w = r0_[3]; p1.w = r1_[3]; }
            }

            const uint2* prow = (const uint2*)&xbuf4[m][sp][0];
            uint2 lo0 = prow[eq],     hi0 = prow[eq + 1];
            uint2 lo1 = prow[eq + 8], hi1 = prow[eq + 9];
            union { uint2 u2[2]; bf16x8 v; } fa0, fa1;
            fa0.u2[0] = lo0; fa0.u2[1] = hi0;
            fa1.u2[0] = lo1; fa1.u2[1] = hi1;

            f32x4 c0_ = __builtin_amdgcn_mfma_f32_16x16x32_bf16(fa0.v, bfr[0][0], zero, 0, 0, 0);
            c0_       = __builtin_amdgcn_mfma_f32_16x16x32_bf16(fa1.v, bfr[0][1], c0_, 0, 0, 0);
            f32x4 c1_ = __builtin_amdgcn_mfma_f32_16x16x32_bf16(fa0.v, bfr[1][0], zero, 0, 0, 0);
            c1_       = __builtin_amdgcn_mfma_f32_16x16x32_bf16(fa1.v, bfr[1][1], c1_, 0, 0, 0);

            f32x4 sq = *(const f32x4*)&sqw[m][16 * w + 4 * q];
            const float pe0[4] = { p0.x, p0.y, p0.z, p0.w };
            const float pe1[4] = { p1.x, p1.y, p1.z, p1.w };
#pragma unroll
            for (int r = 0; r < 4; ++r) {
                float t0v = fmaf(-2.f, c0_[r], sq[r] + ssk0);
                wd0[r] = fmaf(pe0[r], t0v, wd0[r]);
                float t1v = fmaf(-2.f, c1_[r], sq[r] + ssk1);
                wd1[r] = fmaf(pe1[r], t1v, wd1[r]);
            }
        }

        // ---- min: 4 rows -> quads -> LDS cross-wave -> 1 atomic per (b,k) ----
        __syncthreads();                       // sqw reads done; reuse as scratch
        float* red = (float*)&sqw[0][0];       // [4 waves][32]
#pragma unroll
        for (int t = 0; t < 2; ++t) {
            float lmin = __int_as_float(0x7F800000);
            const f32x4 wdv = t ? wd1 : wd0;
#pragma unroll
            for (int r = 0; r < 4; ++r)
                if (nrow + r < N_) lmin = fminf(lmin, wdv[r]);
            lmin = fminf(lmin, __shfl_xor(lmin, 16));
            lmin = fminf(lmin, __shfl_xor(lmin, 32));
            if (q == 0) red[w * 32 + t * 16 + rl] = lmin;
        }
        __syncthreads();
        if (tid < K_) {
            float v = fminf(fminf(red[tid], red[32 + tid]),
                            fminf(red[64 + tid], red[96 + tid]));
            atomicMin(out + (size_t)b * K_ + tid, __float_as_uint(fmaxf(v, 0.f)));
        }
        __syncthreads();   // red reads done before next bb's staging overwrites sqw
    }
}

extern "C" void kernel_launch(void* const* d_in, const int* in_sizes, int n_in,
                              void* d_out, int out_size, void* d_ws, size_t ws_size,
                              hipStream_t stream) {
    const float* x    = (const float*)d_in[0];   // (B, M, T)
    const float* shp  = (const float*)d_in[1];   // (K, L)
    const float* pmap = (const float*)d_in[2];   // (K, M, N)
    unsigned* out = (unsigned*)d_out;            // (B, K) float bits
    float* pen   = (float*)d_ws;                 // (K, M, N) elu(-pmap)+2, 3.9 MB
    float* ss_ws = pen + KMN;                    // (K,) fp32 sum s^2

    pen_init_kernel<<<dim3((KMN / 8 + 255) / 256), dim3(256), 0, stream>>>(
        pmap, shp, pen, ss_ws, out);

    dim3 grid((N_ + TN - 1) / TN, B_ / NBSEQ);   // 32 x 16 = 512 blocks
    shapelet_mfma_kernel<<<grid, dim3(NTH), 0, stream>>>(x, shp, pen, ss_ws, out);
}